// Round 3
// baseline (182.832 us; speedup 1.0000x reference)
//
#include <hip/hip_runtime.h>
#include <hip/hip_fp16.h>

#define N_NODES  100000
#define N_RADIAL 16
#define N_CONICAL 16

#define NPB    256                                   // nodes per bucket
#define NBKT   ((N_NODES + NPB - 1) / NPB)           // 391 buckets
#define NBLK_A 256                                   // binfuse scatter blocks
#define BTHR   512                                   // binfuse block threads
#define SUBCAP 96                                    // per-(block,bucket) sub-run cap
#define BKTSTRIDE (NBLK_A * SUBCAP)                  // 24576 slots per bucket
#define CAP    10240                                 // compacted bucket cap (mean 8192 + 22σ)

// ---------------------------------------------------------------------------
// A. Fused bin+prep (unchanged from R12). Blocks 0..255: single-pass scatter
//    into per-(block,bucket) sub-runs, int4 edge loads = 4 independent
//    atomic->store chains/thread. Block 256: W1/W2 transposes. Blocks 257..:
//    xcon f16 pack (float4 -> uint2).
// ---------------------------------------------------------------------------
__global__ __launch_bounds__(BTHR) void binfuse_kernel(
    const int* __restrict__ idx, const float* __restrict__ x,
    __half2* __restrict__ xcon2,
    const float* __restrict__ W1, const float* __restrict__ W2,
    float* __restrict__ W1t, float* __restrict__ W2t,
    unsigned int* __restrict__ binned, int* __restrict__ cnts,
    int chunk, int total, int E) {
    int b = blockIdx.x, tid = threadIdx.x;
    if (b >= NBLK_A) {
        int pb = b - NBLK_A;
        if (pb == 0) {                       // weight transposes (4096 each)
            for (int i = tid; i < 4096; i += BTHR) {
                int c = i >> 7, k = i & 127;
                W1t[k * 32 + c] = W1[i];     // W1[c][k] -> W1t[k][c]
                int kk = i >> 5, o = i & 31;
                W2t[o * 128 + kk] = W2[i];   // W2[k][o] -> W2t[o][k]
            }
        } else {                             // xcon pack: one float4 -> uint2/thread
            int t = (pb - 1) * BTHR + tid;
            if (t < N_NODES * 4) {
                int n = t >> 2, p = t & 3;
                float4 v = *((const float4*)(x + (size_t)n * 32 + 16) + p);
                __half2 h0 = __floats2half2_rn(v.x, v.y);
                __half2 h1 = __floats2half2_rn(v.z, v.w);
                uint2 st;
                st.x = *(unsigned int*)&h0; st.y = *(unsigned int*)&h1;
                *(uint2*)(xcon2 + 2 * t) = st;
            }
        }
        return;
    }

    __shared__ int cur[NBKT];
    for (int i = tid; i < NBKT; i += BTHR)
        cur[i] = i * BKTSTRIDE + b * SUBCAP;       // absolute slot cursor
    __syncthreads();

    int lo = b * chunk;                    // chunk=12500, E/chunk=128 -> uniform split
    int cofs = (lo >= E) ? -E : E;
    const int4* rp = (const int4*)(idx + lo);
    const int4* cp = (const int4*)(idx + lo + cofs);
    int nq = chunk >> 2;
    #pragma unroll 1
    for (int q = tid; q < nq; q += BTHR) {
        int4 r = rp[q];
        int4 c = cp[q];
        int p0 = atomicAdd(&cur[r.x >> 8], 1);
        int p1 = atomicAdd(&cur[r.y >> 8], 1);
        int p2 = atomicAdd(&cur[r.z >> 8], 1);
        int p3 = atomicAdd(&cur[r.w >> 8], 1);
        binned[p0] = ((unsigned int)(r.x & 255) << 17) | (unsigned int)c.x;
        binned[p1] = ((unsigned int)(r.y & 255) << 17) | (unsigned int)c.y;
        binned[p2] = ((unsigned int)(r.z & 255) << 17) | (unsigned int)c.z;
        binned[p3] = ((unsigned int)(r.w & 255) << 17) | (unsigned int)c.w;
    }
    __syncthreads();

    for (int i = tid; i < NBKT; i += BTHR)
        cnts[i * NBLK_A + b] = cur[i] - (i * BKTSTRIDE + b * SUBCAP);
}

// ---------------------------------------------------------------------------
// B. R13: fused bucket-accumulate + MLP. One block per bucket (256 nodes).
//    Passes 1/3 register-cache the sub-run edges (12 unrolled slots, covers
//    c<=48+l; tail re-reads ~0.3% of cells) — binned is read ONCE. Scan is
//    a single-wave shuffle scan (2 barriers, was 16). Pass 4 accumulates in
//    regs (atomic-free, 2 lanes/node x 16B gathers), hands agg to the MLP
//    through a 16KB LDS stage, then the in-block MLP (port of the verified
//    mlp_kernel at 4 node-groups x 4 k-ranges) writes `out` directly.
//    LDS phases overlay one 64KB region: sedge -> aex -> H2. 66KB, 2 blk/CU.
// ---------------------------------------------------------------------------
__global__ __launch_bounds__(1024, 2) void aggmlp_kernel(
    const __half* __restrict__ xcon, const int* __restrict__ cnts,
    const unsigned int* __restrict__ binned,
    const float* __restrict__ x,
    const float* __restrict__ W1t, const float* __restrict__ b1,
    const float* __restrict__ W2t, const float* __restrict__ b2,
    float* __restrict__ out) {
    __shared__ __align__(16) unsigned char smem[65536];   // sedge | aex | H2
    __shared__ int scnt[NPB];
    __shared__ int soff[NPB];
    unsigned int* sedge = (unsigned int*)smem;            // [CAP] (40KB used)
    float*        aex   = (float*)smem;                   // [16][256] (16KB)
    __half2*      H2    = (__half2*)smem;                 // [64][256] (64KB)

    int b = blockIdx.x, tid = threadIdx.x;
    if (tid < NPB) scnt[tid] = 0;
    __syncthreads();

    int sub = tid >> 2, l = tid & 3;
    int sc  = cnts[b * NBLK_A + sub];
    unsigned int base = (unsigned int)b * BKTSTRIDE + (unsigned int)sub * SUBCAP;

    // pass 1: load+cache sub-run edges, per-node counts
    unsigned int ev[12];
    #pragma unroll
    for (int u = 0; u < 12; u++) {
        int j = l + 4 * u;
        ev[u] = 0u;
        if (j < sc) {
            ev[u] = binned[base + j];
            atomicAdd(&scnt[ev[u] >> 17], 1);
        }
    }
    for (int j = l + 48; j < sc; j += 4)
        atomicAdd(&scnt[binned[base + j] >> 17], 1);
    __syncthreads();

    // pass 2: exclusive scan of 256 counts by wave 0 (shuffle scan, no barriers)
    if (tid < 64) {
        int i0 = tid * 4;
        int c0 = scnt[i0], c1 = scnt[i0 + 1], c2 = scnt[i0 + 2], c3 = scnt[i0 + 3];
        int s = c0 + c1 + c2 + c3;
        int t = s;
        #pragma unroll
        for (int off = 1; off < 64; off <<= 1) {
            int u = __shfl_up(t, off, 64);
            if (tid >= off) t += u;
        }
        int ex = t - s;                      // exclusive prefix of lane sums
        soff[i0]     = ex;
        soff[i0 + 1] = ex + c0;
        soff[i0 + 2] = ex + c0 + c1;
        soff[i0 + 3] = ex + c0 + c1 + c2;
    }
    __syncthreads();

    // pass 3: scatter into node-sorted sedge from the register cache
    #pragma unroll
    for (int u = 0; u < 12; u++) {
        int j = l + 4 * u;
        if (j < sc) {
            unsigned int p = ev[u];
            int pos = atomicAdd(&soff[p >> 17], 1);
            sedge[pos] = p & 0x1FFFFu;
        }
    }
    for (int j = l + 48; j < sc; j += 4) {
        unsigned int p = binned[base + j];
        int pos = atomicAdd(&soff[p >> 17], 1);
        sedge[pos] = p & 0x1FFFFu;
    }
    __syncthreads();

    // pass 4: accumulate, 2 lanes/node, 16B gathers from L2-resident xcon
    int nl = tid >> 1, q = tid & 1;
    float a0 = 0.f, a1 = 0.f, a2 = 0.f, a3 = 0.f;
    float a4 = 0.f, a5 = 0.f, a6 = 0.f, a7 = 0.f;
    int c = 0;
    if (tid < 2 * NPB) {
        c = scnt[nl];
        int s0 = soff[nl] - c;                 // soff advanced to row end
        #pragma unroll 2
        for (int k = 0; k < c; k++) {
            int col = (int)sedge[s0 + k];      // broadcast within pair
            uint4 raw = ((const uint4*)(xcon + (size_t)col * 16))[q];
            float2 f0 = __half22float2(*(const __half2*)&raw.x);
            float2 f1 = __half22float2(*(const __half2*)&raw.y);
            float2 f2 = __half22float2(*(const __half2*)&raw.z);
            float2 f3 = __half22float2(*(const __half2*)&raw.w);
            a0 += f0.x; a1 += f0.y; a2 += f1.x; a3 += f1.y;
            a4 += f2.x; a5 += f2.y; a6 += f3.x; a7 += f3.y;
        }
    }
    __syncthreads();                           // sedge reads done everywhere

    if (tid < 2 * NPB) {                       // hand agg rows to MLP via LDS
        float inv = 1.0f / (float)max(c, 1);
        int j0 = q * 8;
        aex[(j0 + 0) * 256 + nl] = a0 * inv;
        aex[(j0 + 1) * 256 + nl] = a1 * inv;
        aex[(j0 + 2) * 256 + nl] = a2 * inv;
        aex[(j0 + 3) * 256 + nl] = a3 * inv;
        aex[(j0 + 4) * 256 + nl] = a4 * inv;
        aex[(j0 + 5) * 256 + nl] = a5 * inv;
        aex[(j0 + 6) * 256 + nl] = a6 * inv;
        aex[(j0 + 7) * 256 + nl] = a7 * inv;
    }
    __syncthreads();

    // ---------------- in-block MLP (port of verified mlp_kernel) ----------
    int w    = __builtin_amdgcn_readfirstlane(tid >> 6);   // wave 0..15
    int lam  = tid & 63;
    int g    = w & 3;                          // node group (64 nodes)
    int nl2  = g * 64 + lam;
    int n    = b * 256 + nl2;
    int ncl  = min(n, N_NODES - 1);

    float comb[32];
    const float4* xr = (const float4*)(x + (size_t)ncl * 32);
    #pragma unroll
    for (int cc = 0; cc < 4; cc++) {
        float4 v = xr[cc];
        comb[cc*4+0] = v.x; comb[cc*4+1] = v.y;
        comb[cc*4+2] = v.z; comb[cc*4+3] = v.w;
    }
    #pragma unroll
    for (int j = 0; j < 16; j++)
        comb[16 + j] = aex[j * 256 + nl2];
    __syncthreads();                           // aex reads done before H2 writes

    // phase A: wave w computes h[k] for k in [kr, kr+32), wave-uniform -> s_load
    int kr = (w >> 2) * 32;
    #pragma unroll
    for (int i = 0; i < 32; i += 2) {
        int k0 = kr + i;
        const float* w1a = W1t + k0 * 32;
        const float* w1b = w1a + 32;
        float ha = b1[k0], hb = b1[k0 + 1];
        #pragma unroll
        for (int cc = 0; cc < 32; cc++) {
            ha = fmaf(comb[cc], w1a[cc], ha);
            hb = fmaf(comb[cc], w1b[cc], hb);
        }
        ha = fmaxf(ha, 0.f); hb = fmaxf(hb, 0.f);
        H2[(k0 >> 1) * 256 + nl2] = __floats2half2_rn(ha, hb);
    }
    __syncthreads();

    // phase B: wave w computes outs o in [o0, o0+8) for its node group
    int o0 = (w >> 2) * 8;
    const float* w20 = W2t + (o0 + 0) * 128;
    const float* w21 = W2t + (o0 + 1) * 128;
    const float* w22 = W2t + (o0 + 2) * 128;
    const float* w23 = W2t + (o0 + 3) * 128;
    const float* w24 = W2t + (o0 + 4) * 128;
    const float* w25 = W2t + (o0 + 5) * 128;
    const float* w26 = W2t + (o0 + 6) * 128;
    const float* w27 = W2t + (o0 + 7) * 128;
    float acc0 = b2[o0+0], acc1 = b2[o0+1], acc2 = b2[o0+2], acc3 = b2[o0+3];
    float acc4 = b2[o0+4], acc5 = b2[o0+5], acc6 = b2[o0+6], acc7 = b2[o0+7];
    #pragma unroll 4
    for (int kp = 0; kp < 64; kp++) {
        float2 h = __half22float2(H2[kp * 256 + nl2]);
        int k0 = 2 * kp;
        acc0 = fmaf(h.x, w20[k0], acc0); acc0 = fmaf(h.y, w20[k0+1], acc0);
        acc1 = fmaf(h.x, w21[k0], acc1); acc1 = fmaf(h.y, w21[k0+1], acc1);
        acc2 = fmaf(h.x, w22[k0], acc2); acc2 = fmaf(h.y, w22[k0+1], acc2);
        acc3 = fmaf(h.x, w23[k0], acc3); acc3 = fmaf(h.y, w23[k0+1], acc3);
        acc4 = fmaf(h.x, w24[k0], acc4); acc4 = fmaf(h.y, w24[k0+1], acc4);
        acc5 = fmaf(h.x, w25[k0], acc5); acc5 = fmaf(h.y, w25[k0+1], acc5);
        acc6 = fmaf(h.x, w26[k0], acc6); acc6 = fmaf(h.y, w26[k0+1], acc6);
        acc7 = fmaf(h.x, w27[k0], acc7); acc7 = fmaf(h.y, w27[k0+1], acc7);
    }
    if (n < N_NODES) {
        float4 s0v; s0v.x = acc0; s0v.y = acc1; s0v.z = acc2; s0v.w = acc3;
        float4 s1v; s1v.x = acc4; s1v.y = acc5; s1v.z = acc6; s1v.w = acc7;
        float4* op = (float4*)(out + (size_t)n * 32 + o0);
        op[0] = s0v; op[1] = s1v;
    }
}

extern "C" void kernel_launch(void* const* d_in, const int* in_sizes, int n_in,
                              void* d_out, int out_size, void* d_ws, size_t ws_size,
                              hipStream_t stream) {
    const float* x   = (const float*)d_in[0];
    const int*   idx = (const int*)d_in[1];
    const float* W1  = (const float*)d_in[2];
    const float* b1  = (const float*)d_in[3];
    const float* W2  = (const float*)d_in[4];
    const float* b2  = (const float*)d_in[5];
    float* out = (float*)d_out;

    const int E = in_sizes[1] / 2;     // 1,600,000
    const int total = 2 * E;           // 3,200,000
    const int chunk = (total + NBLK_A - 1) / NBLK_A;   // 12,500

    // ws layout (~42 MB):
    //   xcon f16 3.2MB | W1t 16KB | W2t 16KB | cnts 400KB | binned 38.4MB
    char* base = (char*)d_ws;
    __half*       xcon   = (__half*)base;
    float*        W1t    = (float*)(base + 3203072);
    float*        W2t    = (float*)(base + 3219456);
    int*          cnts   = (int*)(base + 3235840);
    unsigned int* binned = (unsigned int*)(base + 3636224);

    int pack_blocks = (N_NODES * 4 + BTHR - 1) / BTHR;   // 782
    binfuse_kernel<<<NBLK_A + 1 + pack_blocks, BTHR, 0, stream>>>(
        idx, x, (__half2*)xcon, W1, W2, W1t, W2t,
        binned, cnts, chunk, total, E);
    aggmlp_kernel<<<NBKT, 1024, 0, stream>>>(
        xcon, cnts, binned, x, W1t, b1, W2t, b2, out);
}

// Round 4
// 171.118 us; speedup vs baseline: 1.0685x; 1.0685x over previous
//
#include <hip/hip_runtime.h>
#include <hip/hip_fp16.h>

#define N_NODES  100000
#define N_RADIAL 16
#define N_CONICAL 16

#define NPB    128                                   // nodes per bucket (R14: halved)
#define NBKT   ((N_NODES + NPB - 1) / NPB)           // 782 buckets
#define NBLK_A 256                                   // binfuse scatter blocks
#define BTHR   1024                                  // binfuse block threads (R14: 2x waves)
#define SUBCAP 48                                    // per-(block,bucket) sub-run cap
                                                     // mean 16, Poisson tail P(>48)~1.7e-11,
                                                     // x200K cells -> ~3e-6/run
#define BKTSTRIDE (NBLK_A * SUBCAP)                  // 12288 slots per bucket
#define CAP    5376                                  // compacted bucket cap (mean 4096 + 20σ)
#define ATHR   512                                   // agg block threads

// ---------------------------------------------------------------------------
// A. Fused bin+prep. Blocks 0..255: single-pass scatter into per-(block,
//    bucket) sub-runs (1 LDS cursor atomic + 1 line-dense write per edge),
//    int4 edge loads = 4 independent atomic->store chains/thread.
//    R14: 1024 threads/block (4 waves/SIMD, was 2) — scatter was
//    latency-bound at Occ 23%. Bucket = row>>7 (NPB=128), payload
//    (row&127)<<17 | col. Block 256: W1/W2 transposes. Blocks 257..:
//    xcon f16 pack (float4 -> uint2).
// ---------------------------------------------------------------------------
__global__ __launch_bounds__(BTHR) void binfuse_kernel(
    const int* __restrict__ idx, const float* __restrict__ x,
    __half2* __restrict__ xcon2,
    const float* __restrict__ W1, const float* __restrict__ W2,
    float* __restrict__ W1t, float* __restrict__ W2t,
    unsigned int* __restrict__ binned, int* __restrict__ cnts,
    int chunk, int total, int E) {
    int b = blockIdx.x, tid = threadIdx.x;
    if (b >= NBLK_A) {
        int pb = b - NBLK_A;
        if (pb == 0) {                       // weight transposes (4096 each)
            for (int i = tid; i < 4096; i += BTHR) {
                int c = i >> 7, k = i & 127;
                W1t[k * 32 + c] = W1[i];     // W1[c][k] -> W1t[k][c]
                int kk = i >> 5, o = i & 31;
                W2t[o * 128 + kk] = W2[i];   // W2[k][o] -> W2t[o][k]
            }
        } else {                             // xcon pack: one float4 -> uint2/thread
            int t = (pb - 1) * BTHR + tid;
            if (t < N_NODES * 4) {
                int n = t >> 2, p = t & 3;
                float4 v = *((const float4*)(x + (size_t)n * 32 + 16) + p);
                __half2 h0 = __floats2half2_rn(v.x, v.y);
                __half2 h1 = __floats2half2_rn(v.z, v.w);
                uint2 st;
                st.x = *(unsigned int*)&h0; st.y = *(unsigned int*)&h1;
                *(uint2*)(xcon2 + 2 * t) = st;
            }
        }
        return;
    }

    __shared__ int cur[NBKT];
    for (int i = tid; i < NBKT; i += BTHR)
        cur[i] = i * BKTSTRIDE + b * SUBCAP;       // absolute slot cursor
    __syncthreads();

    int lo = b * chunk;                    // chunk=12500, E/chunk=128 -> uniform split
    int cofs = (lo >= E) ? -E : E;
    const int4* rp = (const int4*)(idx + lo);
    const int4* cp = (const int4*)(idx + lo + cofs);
    int nq = chunk >> 2;                   // 3125 quads
    #pragma unroll 1
    for (int q = tid; q < nq; q += BTHR) {
        int4 r = rp[q];
        int4 c = cp[q];
        int p0 = atomicAdd(&cur[r.x >> 7], 1);
        int p1 = atomicAdd(&cur[r.y >> 7], 1);
        int p2 = atomicAdd(&cur[r.z >> 7], 1);
        int p3 = atomicAdd(&cur[r.w >> 7], 1);
        binned[p0] = ((unsigned int)(r.x & 127) << 17) | (unsigned int)c.x;
        binned[p1] = ((unsigned int)(r.y & 127) << 17) | (unsigned int)c.y;
        binned[p2] = ((unsigned int)(r.z & 127) << 17) | (unsigned int)c.z;
        binned[p3] = ((unsigned int)(r.w & 127) << 17) | (unsigned int)c.w;
    }
    __syncthreads();

    for (int i = tid; i < NBKT; i += BTHR)
        cnts[i * NBLK_A + b] = cur[i] - (i * BKTSTRIDE + b * SUBCAP);
}

// ---------------------------------------------------------------------------
// B. Bucket accumulate (R12 pass bodies at NPB=128 / 512 threads).
//    R14: 782 blocks x 512 thr -> ~3 blocks/CU avg, 4 resident (22.5KB LDS)
//    — attacks agg's 1-block/CU 135-block tail (was Occ 39%). 256 sub-runs
//    x 2 lanes each; counting sort into sedge; single-wave shuffle scan
//    (2 barriers, verified in R13); atomic-free pass-4 accumulate with
//    2 lanes/node x 16B gathers from L2-resident xcon.
// ---------------------------------------------------------------------------
__global__ __launch_bounds__(ATHR, 4) void agg_kernel(
    const __half* __restrict__ xcon, const int* __restrict__ cnts,
    const unsigned int* __restrict__ binned, __half* __restrict__ agg) {
    __shared__ unsigned int sedge[CAP];   // 21 KB
    __shared__ int scnt[NPB];
    __shared__ int soff[NPB];
    int b = blockIdx.x, tid = threadIdx.x;
    if (tid < NPB) scnt[tid] = 0;
    __syncthreads();

    int sub = tid >> 1, l = tid & 1;      // 256 sub-runs, 2 lanes each
    int sc  = cnts[b * NBLK_A + sub];
    unsigned int base = (unsigned int)b * BKTSTRIDE + (unsigned int)sub * SUBCAP;

    // pass 1: per-node counts
    for (int j = l; j < sc; j += 2)
        atomicAdd(&scnt[binned[base + j] >> 17], 1);
    __syncthreads();

    // pass 2: exclusive scan of 128 counts by wave 0 (shuffle scan)
    if (tid < 64) {
        int i0 = tid * 2;
        int c0 = scnt[i0], c1 = scnt[i0 + 1];
        int s = c0 + c1;
        int t = s;
        #pragma unroll
        for (int off = 1; off < 64; off <<= 1) {
            int u = __shfl_up(t, off, 64);
            if (tid >= off) t += u;
        }
        int ex = t - s;                    // exclusive prefix of lane sums
        soff[i0]     = ex;
        soff[i0 + 1] = ex + c0;
    }
    __syncthreads();

    // pass 3: scatter into node-sorted sedge (L2-hot re-read of sub-runs)
    for (int j = l; j < sc; j += 2) {
        unsigned int p = binned[base + j];
        int pos = atomicAdd(&soff[p >> 17], 1);
        sedge[pos] = p & 0x1FFFFu;
    }
    __syncthreads();

    // pass 4: accumulate, 2 lanes/node, 16B gathers from L2-resident xcon
    if (tid < 2 * NPB) {
        int nl = tid >> 1, q = tid & 1;
        int c  = scnt[nl];
        int s0 = soff[nl] - c;                 // soff advanced to row end
        float a0 = 0.f, a1 = 0.f, a2 = 0.f, a3 = 0.f;
        float a4 = 0.f, a5 = 0.f, a6 = 0.f, a7 = 0.f;
        #pragma unroll 2
        for (int k = 0; k < c; k++) {
            int col = (int)sedge[s0 + k];      // broadcast within pair
            uint4 raw = ((const uint4*)(xcon + (size_t)col * 16))[q];
            float2 f0 = __half22float2(*(const __half2*)&raw.x);
            float2 f1 = __half22float2(*(const __half2*)&raw.y);
            float2 f2 = __half22float2(*(const __half2*)&raw.z);
            float2 f3 = __half22float2(*(const __half2*)&raw.w);
            a0 += f0.x; a1 += f0.y; a2 += f1.x; a3 += f1.y;
            a4 += f2.x; a5 += f2.y; a6 += f3.x; a7 += f3.y;
        }
        int n = b * NPB + nl;
        if (n < N_NODES) {
            float inv = 1.0f / (float)max(c, 1);
            __half2 h0 = __floats2half2_rn(a0 * inv, a1 * inv);
            __half2 h1 = __floats2half2_rn(a2 * inv, a3 * inv);
            __half2 h2 = __floats2half2_rn(a4 * inv, a5 * inv);
            __half2 h3 = __floats2half2_rn(a6 * inv, a7 * inv);
            uint4 st;
            st.x = *(unsigned int*)&h0; st.y = *(unsigned int*)&h1;
            st.z = *(unsigned int*)&h2; st.w = *(unsigned int*)&h3;
            *(uint4*)(agg + (size_t)n * 16 + q * 8) = st;   // 16B/lane
        }
    }
}

// ---------------------------------------------------------------------------
// C. MLP (R9/R10/R12-verified, standalone again): fused two-phase, 8 waves
//    per 64-node tile. Phase A: wave ws computes h[k=ws*16..+15] (k
//    wave-uniform -> W1t on the scalar pipe), h-pairs f16 in LDS
//    H2[kp][node]. Phase B: wave ws computes outs o=ws*4..+3. 12500 waves.
// ---------------------------------------------------------------------------
__global__ __launch_bounds__(512, 4) void mlp_kernel(
    const float* __restrict__ x, const __half* __restrict__ agg,
    const float* __restrict__ W1t, const float* __restrict__ b1,
    const float* __restrict__ W2t, const float* __restrict__ b2,
    float* __restrict__ out, int N) {
    __shared__ __half2 H2[64 * 64];   // [kp][node], 16 KB
    int tid  = threadIdx.x;
    int lane = tid & 63;
    int ws   = __builtin_amdgcn_readfirstlane(tid >> 6);
    int n    = blockIdx.x * 64 + lane;
    int nc   = min(n, N - 1);

    float comb[32];
    const float4* xr = (const float4*)(x + (size_t)nc * 32);
    #pragma unroll
    for (int c = 0; c < 4; c++) {
        float4 v = xr[c];
        comb[c*4+0] = v.x; comb[c*4+1] = v.y;
        comb[c*4+2] = v.z; comb[c*4+3] = v.w;
    }
    const __half2* ar = (const __half2*)(agg + (size_t)nc * 16);
    #pragma unroll
    for (int c = 0; c < 8; c++) {
        float2 f = __half22float2(ar[c]);
        comb[16 + 2*c]     = f.x;
        comb[16 + 2*c + 1] = f.y;
    }

    #pragma unroll
    for (int i = 0; i < 16; i += 2) {
        int k0 = ws * 16 + i;
        const float* w1a = W1t + k0 * 32;
        const float* w1b = w1a + 32;
        float ha = b1[k0], hb = b1[k0 + 1];
        #pragma unroll
        for (int c = 0; c < 32; c++) {
            ha = fmaf(comb[c], w1a[c], ha);
            hb = fmaf(comb[c], w1b[c], hb);
        }
        ha = fmaxf(ha, 0.f); hb = fmaxf(hb, 0.f);
        H2[(k0 >> 1) * 64 + lane] = __floats2half2_rn(ha, hb);
    }
    __syncthreads();

    int o0 = ws * 4;
    const float* w20 = W2t + (o0 + 0) * 128;
    const float* w21 = W2t + (o0 + 1) * 128;
    const float* w22 = W2t + (o0 + 2) * 128;
    const float* w23 = W2t + (o0 + 3) * 128;
    float acc0 = b2[o0+0], acc1 = b2[o0+1], acc2 = b2[o0+2], acc3 = b2[o0+3];
    #pragma unroll 8
    for (int kp = 0; kp < 64; kp++) {
        float2 h = __half22float2(H2[kp * 64 + lane]);
        int k0 = 2 * kp;
        acc0 = fmaf(h.x, w20[k0], acc0); acc0 = fmaf(h.y, w20[k0+1], acc0);
        acc1 = fmaf(h.x, w21[k0], acc1); acc1 = fmaf(h.y, w21[k0+1], acc1);
        acc2 = fmaf(h.x, w22[k0], acc2); acc2 = fmaf(h.y, w22[k0+1], acc2);
        acc3 = fmaf(h.x, w23[k0], acc3); acc3 = fmaf(h.y, w23[k0+1], acc3);
    }
    if (n < N) {
        float* op = out + (size_t)n * 32 + o0;
        op[0] = acc0; op[1] = acc1; op[2] = acc2; op[3] = acc3;
    }
}

extern "C" void kernel_launch(void* const* d_in, const int* in_sizes, int n_in,
                              void* d_out, int out_size, void* d_ws, size_t ws_size,
                              hipStream_t stream) {
    const float* x   = (const float*)d_in[0];
    const int*   idx = (const int*)d_in[1];
    const float* W1  = (const float*)d_in[2];
    const float* b1  = (const float*)d_in[3];
    const float* W2  = (const float*)d_in[4];
    const float* b2  = (const float*)d_in[5];
    float* out = (float*)d_out;

    const int E = in_sizes[1] / 2;     // 1,600,000
    const int total = 2 * E;           // 3,200,000
    const int chunk = (total + NBLK_A - 1) / NBLK_A;   // 12,500

    // ws layout (~46 MB of the 256 MiB workspace):
    //   agg f16 3.2MB | xcon f16 3.2MB | W1t 16KB | W2t 16KB |
    //   cnts 782*256*4 = 800KB | binned 782*12288*4 = 38.4MB
    char* base = (char*)d_ws;
    __half*       agg    = (__half*)base;
    __half*       xcon   = (__half*)(base + 3203072);
    float*        W1t    = (float*)(base + 6406144);
    float*        W2t    = (float*)(base + 6422528);
    int*          cnts   = (int*)(base + 6438912);
    unsigned int* binned = (unsigned int*)(base + 7242752);

    int pack_blocks = (N_NODES * 4 + BTHR - 1) / BTHR;   // 391
    binfuse_kernel<<<NBLK_A + 1 + pack_blocks, BTHR, 0, stream>>>(
        idx, x, (__half2*)xcon, W1, W2, W1t, W2t,
        binned, cnts, chunk, total, E);
    agg_kernel<<<NBKT, ATHR, 0, stream>>>(xcon, cnts, binned, agg);
    mlp_kernel<<<(N_NODES + 63) / 64, 512, 0, stream>>>(
        x, agg, W1t, b1, W2t, b2, out, N_NODES);
}

// Round 5
// 151.582 us; speedup vs baseline: 1.2062x; 1.1289x over previous
//
#include <hip/hip_runtime.h>
#include <hip/hip_fp16.h>

#define N_NODES  100000
#define N_RADIAL 16
#define N_CONICAL 16

#define NPB    256                                   // nodes per bucket
#define NBKT   ((N_NODES + NPB - 1) / NPB)           // 391 buckets
#define NBLK_A 256                                   // binfuse scatter blocks
#define BTHR   512                                   // binfuse block threads
#define CHUNK  12500                                 // edges per scatter block (exact)
#define BINSTRIDE 12544                              // padded block region (392 x 128B lines)
#define CAP    10240                                 // compacted bucket cap (mean 8192 + 22σ)

// ---------------------------------------------------------------------------
// A. R15: in-LDS counting sort per scatter block — eliminates scattered
//    global stores (R14 showed WRITE_SIZE 38->70MB tracks duration: the
//    scatter was partial-line write-amp bound, not occupancy-bound).
//    Each block owns exactly CHUNK=12500 edges (50KB): count per bucket ->
//    wave-0 shuffle scan (391 buckets, 7/lane) -> LDS scatter into dense
//    stage[] -> coalesced full-line flush into block-contiguous binned
//    region (amp 1.0). Exact (bucket,block) starts go to offs[].
//    Block 256: W1/W2 transposes. Blocks 257..: xcon f16 pack.
// ---------------------------------------------------------------------------
__global__ __launch_bounds__(BTHR) void binfuse_kernel(
    const int* __restrict__ idx, const float* __restrict__ x,
    __half2* __restrict__ xcon2,
    const float* __restrict__ W1, const float* __restrict__ W2,
    float* __restrict__ W1t, float* __restrict__ W2t,
    unsigned int* __restrict__ binned, int* __restrict__ cnts,
    int* __restrict__ offs, int total, int E) {
    int b = blockIdx.x, tid = threadIdx.x;
    if (b >= NBLK_A) {
        int pb = b - NBLK_A;
        if (pb == 0) {                       // weight transposes (4096 each)
            for (int i = tid; i < 4096; i += BTHR) {
                int c = i >> 7, k = i & 127;
                W1t[k * 32 + c] = W1[i];     // W1[c][k] -> W1t[k][c]
                int kk = i >> 5, o = i & 31;
                W2t[o * 128 + kk] = W2[i];   // W2[k][o] -> W2t[o][k]
            }
        } else {                             // xcon pack: one float4 -> uint2/thread
            int t = (pb - 1) * BTHR + tid;
            if (t < N_NODES * 4) {
                int n = t >> 2, p = t & 3;
                float4 v = *((const float4*)(x + (size_t)n * 32 + 16) + p);
                __half2 h0 = __floats2half2_rn(v.x, v.y);
                __half2 h1 = __floats2half2_rn(v.z, v.w);
                uint2 st;
                st.x = *(unsigned int*)&h0; st.y = *(unsigned int*)&h1;
                *(uint2*)(xcon2 + 2 * t) = st;
            }
        }
        return;
    }

    __shared__ int cnt[NBKT];
    __shared__ int loff[NBKT];
    __shared__ unsigned int stage[CHUNK];    // 50 KB dense staging
    for (int i = tid; i < NBKT; i += BTHR) cnt[i] = 0;
    __syncthreads();

    int lo = b * CHUNK;                      // E/CHUNK = 128 -> block-uniform split
    int cofs = (lo >= E) ? -E : E;
    const int4* rp = (const int4*)(idx + lo);
    const int4* cp = (const int4*)(idx + lo + cofs);
    int nq = CHUNK >> 2;                     // 3125 quads

    // pass 1: per-bucket counts
    #pragma unroll 1
    for (int q = tid; q < nq; q += BTHR) {
        int4 r = rp[q];
        atomicAdd(&cnt[r.x >> 8], 1);
        atomicAdd(&cnt[r.y >> 8], 1);
        atomicAdd(&cnt[r.z >> 8], 1);
        atomicAdd(&cnt[r.w >> 8], 1);
    }
    __syncthreads();

    // pass 2: exclusive scan over 391 buckets by wave 0 (7 buckets/lane)
    if (tid < 64) {
        int c[7]; int s = 0;
        #pragma unroll
        for (int u = 0; u < 7; u++) {
            int i = tid * 7 + u;
            c[u] = (i < NBKT) ? cnt[i] : 0;
            s += c[u];
        }
        int t = s;
        #pragma unroll
        for (int off = 1; off < 64; off <<= 1) {
            int u = __shfl_up(t, off, 64);
            if (tid >= off) t += u;
        }
        int ex = t - s;
        #pragma unroll
        for (int u = 0; u < 7; u++) {
            int i = tid * 7 + u;
            if (i < NBKT) { loff[i] = ex; ex += c[u]; }
        }
    }
    __syncthreads();

    // publish exact lengths + starts for agg
    for (int i = tid; i < NBKT; i += BTHR) {
        cnts[i * NBLK_A + b] = cnt[i];
        offs[i * NBLK_A + b] = loff[i];
    }
    __syncthreads();                         // loff reads done before cursor use

    // pass 3: scatter into dense LDS stage (loff as cursors)
    #pragma unroll 1
    for (int q = tid; q < nq; q += BTHR) {
        int4 r = rp[q];
        int4 c = cp[q];
        int p0 = atomicAdd(&loff[r.x >> 8], 1);
        int p1 = atomicAdd(&loff[r.y >> 8], 1);
        int p2 = atomicAdd(&loff[r.z >> 8], 1);
        int p3 = atomicAdd(&loff[r.w >> 8], 1);
        stage[p0] = ((unsigned int)(r.x & 255) << 17) | (unsigned int)c.x;
        stage[p1] = ((unsigned int)(r.y & 255) << 17) | (unsigned int)c.y;
        stage[p2] = ((unsigned int)(r.z & 255) << 17) | (unsigned int)c.z;
        stage[p3] = ((unsigned int)(r.w & 255) << 17) | (unsigned int)c.w;
    }
    __syncthreads();

    // pass 4: coalesced full-line flush (write amp 1.0)
    unsigned int* dst = binned + (size_t)b * BINSTRIDE;
    for (int i = tid; i < CHUNK; i += BTHR) dst[i] = stage[i];
}

// ---------------------------------------------------------------------------
// B. Bucket accumulate (R12-verified pass bodies). Only change: sub-run
//    base comes from offs[] (dense block-contiguous binned regions) instead
//    of fixed-capacity cells — re-reads are now dense ~128B runs.
//    256 sub-runs x 4 lanes; counting sort into sedge; single-wave shuffle
//    scan; atomic-free pass-4 accumulate, 2 lanes/node x 16B gathers.
// ---------------------------------------------------------------------------
__global__ __launch_bounds__(1024, 2) void agg_kernel(
    const __half* __restrict__ xcon, const int* __restrict__ cnts,
    const int* __restrict__ offs,
    const unsigned int* __restrict__ binned, __half* __restrict__ agg) {
    __shared__ unsigned int sedge[CAP];   // 40 KB
    __shared__ int scnt[NPB];
    __shared__ int soff[NPB];
    int b = blockIdx.x, tid = threadIdx.x;
    if (tid < NPB) scnt[tid] = 0;
    __syncthreads();

    int sub = tid >> 2, l = tid & 3;
    int sc  = cnts[b * NBLK_A + sub];
    unsigned int base = (unsigned int)sub * BINSTRIDE
                      + (unsigned int)offs[b * NBLK_A + sub];

    // pass 1: per-node counts
    for (int j = l; j < sc; j += 4)
        atomicAdd(&scnt[binned[base + j] >> 17], 1);
    __syncthreads();

    // pass 2: exclusive scan of 256 counts by wave 0 (shuffle scan)
    if (tid < 64) {
        int i0 = tid * 4;
        int c0 = scnt[i0], c1 = scnt[i0 + 1], c2 = scnt[i0 + 2], c3 = scnt[i0 + 3];
        int s = c0 + c1 + c2 + c3;
        int t = s;
        #pragma unroll
        for (int off = 1; off < 64; off <<= 1) {
            int u = __shfl_up(t, off, 64);
            if (tid >= off) t += u;
        }
        int ex = t - s;
        soff[i0]     = ex;
        soff[i0 + 1] = ex + c0;
        soff[i0 + 2] = ex + c0 + c1;
        soff[i0 + 3] = ex + c0 + c1 + c2;
    }
    __syncthreads();

    // pass 3: scatter into node-sorted sedge (L2-hot dense re-read)
    for (int j = l; j < sc; j += 4) {
        unsigned int p = binned[base + j];
        int pos = atomicAdd(&soff[p >> 17], 1);
        sedge[pos] = p & 0x1FFFFu;
    }
    __syncthreads();

    // pass 4: accumulate, 2 lanes/node, 16B gathers from L2-resident xcon
    if (tid < 2 * NPB) {
        int nl = tid >> 1, q = tid & 1;
        int c  = scnt[nl];
        int s0 = soff[nl] - c;                 // soff advanced to row end
        float a0 = 0.f, a1 = 0.f, a2 = 0.f, a3 = 0.f;
        float a4 = 0.f, a5 = 0.f, a6 = 0.f, a7 = 0.f;
        #pragma unroll 2
        for (int k = 0; k < c; k++) {
            int col = (int)sedge[s0 + k];      // broadcast within pair
            uint4 raw = ((const uint4*)(xcon + (size_t)col * 16))[q];
            float2 f0 = __half22float2(*(const __half2*)&raw.x);
            float2 f1 = __half22float2(*(const __half2*)&raw.y);
            float2 f2 = __half22float2(*(const __half2*)&raw.z);
            float2 f3 = __half22float2(*(const __half2*)&raw.w);
            a0 += f0.x; a1 += f0.y; a2 += f1.x; a3 += f1.y;
            a4 += f2.x; a5 += f2.y; a6 += f3.x; a7 += f3.y;
        }
        int n = b * NPB + nl;
        if (n < N_NODES) {
            float inv = 1.0f / (float)max(c, 1);
            __half2 h0 = __floats2half2_rn(a0 * inv, a1 * inv);
            __half2 h1 = __floats2half2_rn(a2 * inv, a3 * inv);
            __half2 h2 = __floats2half2_rn(a4 * inv, a5 * inv);
            __half2 h3 = __floats2half2_rn(a6 * inv, a7 * inv);
            uint4 st;
            st.x = *(unsigned int*)&h0; st.y = *(unsigned int*)&h1;
            st.z = *(unsigned int*)&h2; st.w = *(unsigned int*)&h3;
            *(uint4*)(agg + (size_t)n * 16 + q * 8) = st;   // 16B/lane
        }
    }
}

// ---------------------------------------------------------------------------
// C. MLP (R9/R10/R12-verified): fused two-phase, 8 waves per 64-node tile.
//    Phase A: wave ws computes h[k=ws*16..+15] (k wave-uniform -> W1t on the
//    scalar pipe), h-pairs f16 in LDS H2[kp][node]. Phase B: wave ws
//    computes outs o=ws*4..+3. 12500 waves.
// ---------------------------------------------------------------------------
__global__ __launch_bounds__(512, 4) void mlp_kernel(
    const float* __restrict__ x, const __half* __restrict__ agg,
    const float* __restrict__ W1t, const float* __restrict__ b1,
    const float* __restrict__ W2t, const float* __restrict__ b2,
    float* __restrict__ out, int N) {
    __shared__ __half2 H2[64 * 64];   // [kp][node], 16 KB
    int tid  = threadIdx.x;
    int lane = tid & 63;
    int ws   = __builtin_amdgcn_readfirstlane(tid >> 6);
    int n    = blockIdx.x * 64 + lane;
    int nc   = min(n, N - 1);

    float comb[32];
    const float4* xr = (const float4*)(x + (size_t)nc * 32);
    #pragma unroll
    for (int c = 0; c < 4; c++) {
        float4 v = xr[c];
        comb[c*4+0] = v.x; comb[c*4+1] = v.y;
        comb[c*4+2] = v.z; comb[c*4+3] = v.w;
    }
    const __half2* ar = (const __half2*)(agg + (size_t)nc * 16);
    #pragma unroll
    for (int c = 0; c < 8; c++) {
        float2 f = __half22float2(ar[c]);
        comb[16 + 2*c]     = f.x;
        comb[16 + 2*c + 1] = f.y;
    }

    #pragma unroll
    for (int i = 0; i < 16; i += 2) {
        int k0 = ws * 16 + i;
        const float* w1a = W1t + k0 * 32;
        const float* w1b = w1a + 32;
        float ha = b1[k0], hb = b1[k0 + 1];
        #pragma unroll
        for (int c = 0; c < 32; c++) {
            ha = fmaf(comb[c], w1a[c], ha);
            hb = fmaf(comb[c], w1b[c], hb);
        }
        ha = fmaxf(ha, 0.f); hb = fmaxf(hb, 0.f);
        H2[(k0 >> 1) * 64 + lane] = __floats2half2_rn(ha, hb);
    }
    __syncthreads();

    int o0 = ws * 4;
    const float* w20 = W2t + (o0 + 0) * 128;
    const float* w21 = W2t + (o0 + 1) * 128;
    const float* w22 = W2t + (o0 + 2) * 128;
    const float* w23 = W2t + (o0 + 3) * 128;
    float acc0 = b2[o0+0], acc1 = b2[o0+1], acc2 = b2[o0+2], acc3 = b2[o0+3];
    #pragma unroll 8
    for (int kp = 0; kp < 64; kp++) {
        float2 h = __half22float2(H2[kp * 64 + lane]);
        int k0 = 2 * kp;
        acc0 = fmaf(h.x, w20[k0], acc0); acc0 = fmaf(h.y, w20[k0+1], acc0);
        acc1 = fmaf(h.x, w21[k0], acc1); acc1 = fmaf(h.y, w21[k0+1], acc1);
        acc2 = fmaf(h.x, w22[k0], acc2); acc2 = fmaf(h.y, w22[k0+1], acc2);
        acc3 = fmaf(h.x, w23[k0], acc3); acc3 = fmaf(h.y, w23[k0+1], acc3);
    }
    if (n < N) {
        float* op = out + (size_t)n * 32 + o0;
        op[0] = acc0; op[1] = acc1; op[2] = acc2; op[3] = acc3;
    }
}

extern "C" void kernel_launch(void* const* d_in, const int* in_sizes, int n_in,
                              void* d_out, int out_size, void* d_ws, size_t ws_size,
                              hipStream_t stream) {
    const float* x   = (const float*)d_in[0];
    const int*   idx = (const int*)d_in[1];
    const float* W1  = (const float*)d_in[2];
    const float* b1  = (const float*)d_in[3];
    const float* W2  = (const float*)d_in[4];
    const float* b2  = (const float*)d_in[5];
    float* out = (float*)d_out;

    const int E = in_sizes[1] / 2;     // 1,600,000
    const int total = 2 * E;           // 3,200,000

    // ws layout (~20.1 MB):
    //   agg f16 3.2MB | xcon f16 3.2MB | W1t 16KB | W2t 16KB |
    //   cnts 391*256*4 = 400KB | offs 400KB | binned 256*12544*4 = 12.85MB
    char* base = (char*)d_ws;
    __half*       agg    = (__half*)base;
    __half*       xcon   = (__half*)(base + 3203072);
    float*        W1t    = (float*)(base + 6406144);
    float*        W2t    = (float*)(base + 6422528);
    int*          cnts   = (int*)(base + 6438912);
    int*          offs   = (int*)(base + 6839296);
    unsigned int* binned = (unsigned int*)(base + 7239680);

    int pack_blocks = (N_NODES * 4 + BTHR - 1) / BTHR;   // 782
    binfuse_kernel<<<NBLK_A + 1 + pack_blocks, BTHR, 0, stream>>>(
        idx, x, (__half2*)xcon, W1, W2, W1t, W2t,
        binned, cnts, offs, total, E);
    agg_kernel<<<NBKT, 1024, 0, stream>>>(xcon, cnts, offs, binned, agg);
    mlp_kernel<<<(N_NODES + 63) / 64, 512, 0, stream>>>(
        x, agg, W1t, b1, W2t, b2, out, N_NODES);
}